// Round 16
// baseline (251.494 us; speedup 1.0000x reference)
//
#include <hip/hip_runtime.h>
#include <math.h>
#include <stdint.h>

#define NI 100000   // N_ITEMS
#define NB 512      // batch
#define NH 256      // hidden H
#define H3 768      // 3*H

typedef _Float16 f16x8 __attribute__((ext_vector_type(8)));
typedef float    f32x4 __attribute__((ext_vector_type(4)));

__device__ __forceinline__ float tanh_fast(float x) {
    x = fminf(fmaxf(x, -9.0f), 9.0f);
    const float e = __expf(2.0f * x);
    return (e - 1.0f) * __builtin_amdgcn_rcpf(e + 1.0f);
}
__device__ __forceinline__ float sigmoid_fast(float x) {
    return 1.0f / (1.0f + __expf(-x));
}

// ---------------- layer 2 gates: emits hnew[2] + fp16 copy for the MFMA GEMM --------
__global__ void k_gates_last(const float* __restrict__ xp,
                             const float* __restrict__ hp,
                             const float* __restrict__ hprev,
                             float* __restrict__ hnew,
                             _Float16* __restrict__ Xh)    // (512,256) fp16
{
    const int b = blockIdx.x;
    const int j = threadIdx.x;
    const float xr = xp[b * H3 + j];
    const float xz = xp[b * H3 + NH + j];
    const float xn = xp[b * H3 + 2 * NH + j];
    const float hr = hp[b * H3 + j];
    const float hz = hp[b * H3 + NH + j];
    const float hn = hp[b * H3 + 2 * NH + j];
    const float h  = hprev[b * NH + j];
    const float r = sigmoid_fast(xr + hr);
    const float z = sigmoid_fast(xz + hz);
    const float n = tanh_fast(xn + r * hn);
    const float v = (1.0f - z) * n + z * h;
    hnew[b * NH + j] = v;
    Xh[b * NH + j] = (_Float16)v;
}

// ---------------- small tiled fp32 GEMM:  C = A @ B.T + bias (z-batched, hp) --------
__global__ __launch_bounds__(256)
void k_gemm_small(const float* __restrict__ A0,
                  const float* __restrict__ B0,
                  const float* __restrict__ bias0,
                  float* __restrict__ C0,
                  int M, int N, int K,
                  int sA, int sB, int sBias, int sC)
{
    constexpr int BM = 64, BN = 64, BK = 64;
    __shared__ float As[BK][BM];
    __shared__ float Bs[BK][BN];

    const float* A    = A0 + (size_t)blockIdx.z * sA;
    const float* Bm   = B0 + (size_t)blockIdx.z * sB;
    const float* bias = bias0 + (size_t)blockIdx.z * sBias;
    float*       C    = C0 + (size_t)blockIdx.z * sC;

    const int tid = threadIdx.x;
    const int tx  = tid & 15;
    const int ty  = tid >> 4;
    const int m0  = blockIdx.x * BM;
    const int n0  = blockIdx.y * BN;

    float acc[4][4];
#pragma unroll
    for (int i = 0; i < 4; i++)
#pragma unroll
        for (int j = 0; j < 4; j++) acc[i][j] = 0.0f;

    for (int k0 = 0; k0 < K; k0 += BK) {
#pragma unroll
        for (int f = 0; f < 4; f++) {
            const int fid = tid + f * 256;
            const int row = fid >> 4;
            const int t4  = fid & 15;
            const int mp  = row ^ ((t4 & 3) << 3);
            {
                const float4 v = *(const float4*)(A + (size_t)(m0 + row) * K + k0 + t4 * 4);
                As[t4 * 4 + 0][mp] = v.x; As[t4 * 4 + 1][mp] = v.y;
                As[t4 * 4 + 2][mp] = v.z; As[t4 * 4 + 3][mp] = v.w;
            }
            {
                const float4 v = *(const float4*)(Bm + (size_t)(n0 + row) * K + k0 + t4 * 4);
                Bs[t4 * 4 + 0][mp] = v.x; Bs[t4 * 4 + 1][mp] = v.y;
                Bs[t4 * 4 + 2][mp] = v.z; Bs[t4 * 4 + 3][mp] = v.w;
            }
        }
        __syncthreads();
#pragma unroll
        for (int kk = 0; kk < BK; kk++) {
            const int s = ((kk >> 2) & 3) << 3;
            const float4 a0 = *(const float4*)&As[kk][(ty * 4) ^ s];
            const float4 b0 = *(const float4*)&Bs[kk][(tx * 4) ^ s];
            const float av[4] = {a0.x, a0.y, a0.z, a0.w};
            const float bv[4] = {b0.x, b0.y, b0.z, b0.w};
#pragma unroll
            for (int i = 0; i < 4; i++)
#pragma unroll
                for (int j = 0; j < 4; j++)
                    acc[i][j] = fmaf(av[i], bv[j], acc[i][j]);
        }
        __syncthreads();
    }

#pragma unroll
    for (int i = 0; i < 4; i++) {
        const size_t rowoff = (size_t)(m0 + ty * 4 + i) * N;
        const int gn = n0 + tx * 4;
        const float4 bb = *(const float4*)(bias + gn);
        float4 v;
        v.x = acc[i][0] + bb.x; v.y = acc[i][1] + bb.y;
        v.z = acc[i][2] + bb.z; v.w = acc[i][3] + bb.w;
        *(float4*)(C + rowoff + gn) = v;
    }
}

// ---------------- fused gates + x_proj GEMM ----------------
// xp_out[b][n] = sum_j gates_l(b,j) * Wih[n][j] + bias[n]; blocks with n0==0 also
// write hnew_l. MODE 0: gates from Wih0-gather (layer 0); MODE 1: gates from xprev
// (xp of previous layer). Gates recomputed per n-block (12x) — elementwise,
// L2-resident. Kills 2 serial launches from the chain.
template<int MODE>
__global__ __launch_bounds__(256)
void k_gemm_fused(const int* __restrict__ idx,
                  const float* __restrict__ Wih0,    // (768,NI)   [MODE 0]
                  const float* __restrict__ bih0,    // (768)      [MODE 0]
                  const float* __restrict__ xprev,   // (512,768)  [MODE 1]
                  const float* __restrict__ hpl,     // (512,768) h-projection, layer l
                  const float* __restrict__ hprev,   // (512,256) hidden[l]
                  const float* __restrict__ Bm,      // (768,256) WihHi[l]
                  const float* __restrict__ bias,    // (768) bih[l+1]
                  float* __restrict__ hnew_out,      // (512,256) hnew[l]
                  float* __restrict__ xp_out)        // (512,768)
{
    constexpr int BM = 64, BN = 64, BK = 64;
    __shared__ float As[BK][BM];
    __shared__ float Bs[BK][BN];

    const int tid = threadIdx.x;
    const int tx  = tid & 15;
    const int ty  = tid >> 4;
    const int m0  = blockIdx.x * BM;
    const int n0  = blockIdx.y * BN;

    float acc[4][4];
#pragma unroll
    for (int i = 0; i < 4; i++)
#pragma unroll
        for (int j = 0; j < 4; j++) acc[i][j] = 0.0f;

    for (int k0 = 0; k0 < NH; k0 += BK) {
#pragma unroll
        for (int f = 0; f < 4; f++) {
            const int fid = tid + f * 256;       // 0..1023
            const int row = fid >> 4;            // 0..63
            const int t4  = fid & 15;
            const int mp  = row ^ ((t4 & 3) << 3);
            const int b   = m0 + row;
            const int j0  = k0 + t4 * 4;

            // ---- A element = GRU gate output, computed inline ----
            float xr[4], xz[4], xn[4];
            if (MODE == 0) {
                const int ib = idx[b];
#pragma unroll
                for (int e = 0; e < 4; e++) {
                    xr[e] = Wih0[(size_t)(j0 + e) * NI + ib]          + bih0[j0 + e];
                    xz[e] = Wih0[(size_t)(j0 + e + NH) * NI + ib]     + bih0[j0 + e + NH];
                    xn[e] = Wih0[(size_t)(j0 + e + 2 * NH) * NI + ib] + bih0[j0 + e + 2 * NH];
                }
            } else {
                const float4 a = *(const float4*)(xprev + (size_t)b * H3 + j0);
                const float4 c = *(const float4*)(xprev + (size_t)b * H3 + NH + j0);
                const float4 d = *(const float4*)(xprev + (size_t)b * H3 + 2 * NH + j0);
                xr[0]=a.x; xr[1]=a.y; xr[2]=a.z; xr[3]=a.w;
                xz[0]=c.x; xz[1]=c.y; xz[2]=c.z; xz[3]=c.w;
                xn[0]=d.x; xn[1]=d.y; xn[2]=d.z; xn[3]=d.w;
            }
            const float4 hr4 = *(const float4*)(hpl + (size_t)b * H3 + j0);
            const float4 hz4 = *(const float4*)(hpl + (size_t)b * H3 + NH + j0);
            const float4 hn4 = *(const float4*)(hpl + (size_t)b * H3 + 2 * NH + j0);
            const float4 h4  = *(const float4*)(hprev + (size_t)b * NH + j0);
            const float hr[4] = {hr4.x, hr4.y, hr4.z, hr4.w};
            const float hz[4] = {hz4.x, hz4.y, hz4.z, hz4.w};
            const float hn[4] = {hn4.x, hn4.y, hn4.z, hn4.w};
            const float hh[4] = {h4.x, h4.y, h4.z, h4.w};
            float av[4];
#pragma unroll
            for (int e = 0; e < 4; e++) {
                const float r = sigmoid_fast(xr[e] + hr[e]);
                const float z = sigmoid_fast(xz[e] + hz[e]);
                const float n = tanh_fast(xn[e] + r * hn[e]);
                av[e] = (1.0f - z) * n + z * hh[e];
            }
            As[t4 * 4 + 0][mp] = av[0]; As[t4 * 4 + 1][mp] = av[1];
            As[t4 * 4 + 2][mp] = av[2]; As[t4 * 4 + 3][mp] = av[3];
            if (n0 == 0) {
                float4 o; o.x = av[0]; o.y = av[1]; o.z = av[2]; o.w = av[3];
                *(float4*)(hnew_out + (size_t)b * NH + j0) = o;
            }
            // ---- B tile ----
            {
                const float4 v = *(const float4*)(Bm + (size_t)(n0 + row) * NH + k0 + t4 * 4);
                Bs[t4 * 4 + 0][mp] = v.x; Bs[t4 * 4 + 1][mp] = v.y;
                Bs[t4 * 4 + 2][mp] = v.z; Bs[t4 * 4 + 3][mp] = v.w;
            }
        }
        __syncthreads();
#pragma unroll
        for (int kk = 0; kk < BK; kk++) {
            const int s = ((kk >> 2) & 3) << 3;
            const float4 a0 = *(const float4*)&As[kk][(ty * 4) ^ s];
            const float4 b0 = *(const float4*)&Bs[kk][(tx * 4) ^ s];
            const float av[4] = {a0.x, a0.y, a0.z, a0.w};
            const float bv[4] = {b0.x, b0.y, b0.z, b0.w};
#pragma unroll
            for (int i = 0; i < 4; i++)
#pragma unroll
                for (int j = 0; j < 4; j++)
                    acc[i][j] = fmaf(av[i], bv[j], acc[i][j]);
        }
        __syncthreads();
    }

#pragma unroll
    for (int i = 0; i < 4; i++) {
        const size_t rowoff = (size_t)(m0 + ty * 4 + i) * H3;
        const int gn = n0 + tx * 4;
        const float4 bb = *(const float4*)(bias + gn);
        float4 v;
        v.x = acc[i][0] + bb.x; v.y = acc[i][1] + bb.y;
        v.z = acc[i][2] + bb.z; v.w = acc[i][3] + bb.w;
        *(float4*)(xp_out + rowoff + gn) = v;
    }
}

// ---------------- output projection: act = tanh(x @ Wout.T + bout), fp16 MFMA ----------
// R16 = R15 kernel with 2n x 4m wave split: wave w -> p=w>>2 (m-half & epilogue pass),
// wmh=(w>>1)&1 (m-quarter), wn2=w&1 (n-half). Each wave reads only HALF the W panel
// -> K-loop LDS traffic 512->256 KB/tile, cvts halved; MFMA count unchanged
// (acc[2][8] = 64 AGPR). X L1 reads double (L2-absorbed). NT stores kept (R15 win).
// (512,4): 64 arch VGPR cap + 64 AGPR acc = 128/wave -> 2 blocks/CU, no spill.
// mfma(A=W, B=X): D row((lane>>4)*4+reg)=n within frag, col(lane&15)=m within frag
// (verified r1-r15): n = n0 + wn2*32 + nf*16 + lg*4 + r, m = p*256 + wmh*128 + mf*16 + lr.
__global__ __launch_bounds__(512, 4)
void k_out_mfma(const _Float16* __restrict__ Xh,  // (512,256) fp16
                const float* __restrict__ W,      // (NI,256) fp32
                const float* __restrict__ bout,   // (NI)
                float* __restrict__ C)            // (512,NI)
{
    __shared__ __align__(16) float S[16384];   // 64 KB: W panel, then C half-tiles

    const int n0   = blockIdx.x * 64;          // n-tile base (1563 tiles)
    const int tid  = threadIdx.x;
    const int w    = tid >> 6;
    const int lane = tid & 63;
    const int lr   = lane & 15;
    const int lg   = lane >> 4;                // 0..3
    const int p    = w >> 2;                   // m-half / epilogue pass
    const int wmh  = (w >> 1) & 1;             // m-quarter within half
    const int wn2  = w & 1;                    // n-half

    // ---- stage W panel: 64 rows x 64 16B-chunks (1KB-contiguous per wave-instr) ----
#pragma unroll
    for (int it = 0; it < 8; ++it) {
        const int fid = it * 512 + tid;        // chunk id 0..4095
        const int row = fid >> 6;              // 0..63
        const int pc  = fid & 63;              // physical chunk in LDS row
        int gr = n0 + row; if (gr >= NI) gr = NI - 1;      // clamp; cols masked later
        const float* src = W + (size_t)gr * NH + (size_t)(pc ^ (row & 7)) * 4;
        __builtin_amdgcn_global_load_lds(
            (const __attribute__((address_space(1))) void*)src,
            (__attribute__((address_space(3))) void*)(S + fid * 4),
            16, 0, 0);
    }

    f32x4 acc[2][8];
#pragma unroll
    for (int nf = 0; nf < 2; ++nf)
#pragma unroll
        for (int mf = 0; mf < 8; ++mf) acc[nf][mf] = (f32x4){0.f, 0.f, 0.f, 0.f};

    __syncthreads();

    const _Float16* xbase = Xh + (size_t)(p * 256 + wmh * 128 + lr) * NH + lg * 8;

    // ---- K-loop: 8 steps, no barriers; 2 W frags (half panel) + 8 X frags per step ----
#pragma unroll
    for (int t = 0; t < 8; ++t) {
        f16x8 wf[2];
#pragma unroll
        for (int nf = 0; nf < 2; ++nf) {
            const int rl = wn2 * 32 + nf * 16 + lr;           // W-panel row (this n-half)
            const int c0 = t * 8 + ((lg * 2)     ^ (rl & 7)); // phys chunk (undo swizzle)
            const int c1 = t * 8 + ((lg * 2 + 1) ^ (rl & 7));
            const f32x4 u0 = *(const f32x4*)(S + rl * 256 + c0 * 4);
            const f32x4 u1 = *(const f32x4*)(S + rl * 256 + c1 * 4);
            f16x8 h;
            h[0] = (_Float16)u0[0]; h[1] = (_Float16)u0[1];
            h[2] = (_Float16)u0[2]; h[3] = (_Float16)u0[3];
            h[4] = (_Float16)u1[0]; h[5] = (_Float16)u1[1];
            h[6] = (_Float16)u1[2]; h[7] = (_Float16)u1[3];
            wf[nf] = h;
        }
#pragma unroll
        for (int mf = 0; mf < 8; ++mf) {
            const f16x8 xf = *(const f16x8*)(xbase + mf * 16 * NH + t * 32);
            acc[0][mf] = __builtin_amdgcn_mfma_f32_16x16x32_f16(wf[0], xf, acc[0][mf], 0, 0, 0);
            acc[1][mf] = __builtin_amdgcn_mfma_f32_16x16x32_f16(wf[1], xf, acc[1][mf], 0, 0, 0);
        }
    }

    // ---- epilogue: 2 passes (256 rows each) via LDS; 256B-contiguous NT stores ----
#pragma unroll
    for (int pass = 0; pass < 2; ++pass) {
        __syncthreads();                       // pass 0: all k-loop LDS reads done
        if (p == pass) {
#pragma unroll
            for (int nf = 0; nf < 2; ++nf) {
                const int gn = n0 + wn2 * 32 + nf * 16 + lg * 4;
                const float4 bb = (gn < NI) ? *(const float4*)(bout + gn)
                                            : make_float4(0.f, 0.f, 0.f, 0.f);
                const int q = wn2 * 8 + nf * 4 + lg;          // float4 slot 0..15
#pragma unroll
                for (int mf = 0; mf < 8; ++mf) {
                    const int mr   = wmh * 128 + mf * 16 + lr; // 0..255
                    const int slot = q ^ (lr & 7);
                    float4 v;
                    v.x = tanh_fast(acc[nf][mf][0] + bb.x);
                    v.y = tanh_fast(acc[nf][mf][1] + bb.y);
                    v.z = tanh_fast(acc[nf][mf][2] + bb.z);
                    v.w = tanh_fast(acc[nf][mf][3] + bb.w);
                    *(float4*)(S + mr * 64 + slot * 4) = v;
                }
            }
        }
        __syncthreads();
#pragma unroll
        for (int it = 0; it < 8; ++it) {
            const int fid = it * 512 + tid;    // 0..4095
            const int row = fid >> 4;          // 0..255
            const int c   = fid & 15;          // logical float4 chunk
            const int gn  = n0 + c * 4;
            if (gn < NI) {
                const f32x4 v = *(const f32x4*)(S + row * 64 + ((c ^ (row & 7)) * 4));
                __builtin_nontemporal_store(
                    v, (f32x4*)(C + (size_t)(pass * 256 + row) * NI + gn));
            }
        }
    }
}

extern "C" void kernel_launch(void* const* d_in, const int* in_sizes, int n_in,
                              void* d_out, int out_size, void* d_ws, size_t ws_size,
                              hipStream_t stream)
{
    const int*   idx    = (const int*)  d_in[0];
    const float* hidden = (const float*)d_in[1];   // (3,512,256)
    const float* Wih0   = (const float*)d_in[2];   // (768,100000)
    const float* WihHi  = (const float*)d_in[3];   // (2,768,256)
    const float* Whh    = (const float*)d_in[4];   // (3,768,256)
    const float* bih    = (const float*)d_in[5];   // (3,768)
    const float* bhh    = (const float*)d_in[6];   // (3,768)
    const float* Wout   = (const float*)d_in[7];   // (100000,256)
    const float* bout   = (const float*)d_in[8];   // (100000)

    float* act  = (float*)d_out;                  // (512, NI)
    float* hnew = act + (size_t)NB * NI;          // (3,512,256)
    // fp32 scratch lives in the activation region; final GEMM overwrites it.
    float* hp  = act;                             // (3,512,768)
    float* xp1 = act + 3 * NB * H3;               // (512,768)
    float* xp2 = xp1 + NB * H3;                   // (512,768)
    // fp16 X lives in d_ws (must survive while the big GEMM writes act)
    _Float16* Xh = (_Float16*)d_ws;               // (512,256) = 256 KB

    const dim3 bs(256);
    const dim3 gs_hp(NB / 64, H3 / 64, 3);
    const dim3 gs_xp(NB / 64, H3 / 64, 1);

    // ---- all hidden-projections (depend only on input `hidden`) ----
    k_gemm_small<<<gs_hp, bs, 0, stream>>>(hidden, Whh, bhh, hp,
                                           NB, H3, NH, NB * NH, H3 * NH, H3, NB * H3);
    // ---- layer 1 GEMM with layer-0 gates fused into A-load (writes hnew[0] + xp1) ----
    k_gemm_fused<0><<<gs_xp, bs, 0, stream>>>(idx, Wih0, bih, nullptr,
                                              hp, hidden, WihHi, bih + H3,
                                              hnew, xp1);
    // ---- layer 2 GEMM with layer-1 gates fused into A-load (writes hnew[1] + xp2) ----
    k_gemm_fused<1><<<gs_xp, bs, 0, stream>>>(nullptr, nullptr, nullptr, xp1,
                                              hp + NB * H3, hidden + NB * NH,
                                              WihHi + H3 * NH, bih + 2 * H3,
                                              hnew + NB * NH, xp2);
    // ---- layer 2 gates (hnew[2] + fp16 Xh) ----
    k_gates_last<<<NB, bs, 0, stream>>>(xp2, hp + 2 * NB * H3, hidden + 2 * NB * NH,
                                        hnew + 2 * NB * NH, Xh);
    // ---- output projection: 1563 n-tiles of 64, whole batch per block ----
    k_out_mfma<<<dim3((NI + 63) / 64), dim3(512), 0, stream>>>(Xh, Wout, bout, act);
}

// Round 17
// 155.268 us; speedup vs baseline: 1.6197x; 1.6197x over previous
//
#include <hip/hip_runtime.h>
#include <math.h>
#include <stdint.h>

#define NI 100000   // N_ITEMS
#define NB 512      // batch
#define NH 256      // hidden H
#define H3 768      // 3*H

typedef _Float16 f16x8 __attribute__((ext_vector_type(8)));
typedef float    f32x4 __attribute__((ext_vector_type(4)));

__device__ __forceinline__ float tanh_fast(float x) {
    x = fminf(fmaxf(x, -9.0f), 9.0f);
    const float e = __expf(2.0f * x);
    return (e - 1.0f) * __builtin_amdgcn_rcpf(e + 1.0f);
}
__device__ __forceinline__ float sigmoid_fast(float x) {
    return 1.0f / (1.0f + __expf(-x));
}

// ---------------- GRU gate elementwise (layer 0: gather x_proj inline, done ONCE) ----
__global__ void k_gates0(const int* __restrict__ idx,
                         const float* __restrict__ Wih0,   // (768, NI)
                         const float* __restrict__ bih0,   // (768)
                         const float* __restrict__ hp,     // (512,768)
                         const float* __restrict__ hprev,  // (512,256)
                         float* __restrict__ hnew)         // (512,256)
{
    const int b = blockIdx.x;
    const int j = threadIdx.x;          // 0..255
    const int ib = idx[b];
    const float xr = Wih0[(size_t)(j          ) * NI + ib] + bih0[j];
    const float xz = Wih0[(size_t)(j + NH     ) * NI + ib] + bih0[j + NH];
    const float xn = Wih0[(size_t)(j + 2 * NH ) * NI + ib] + bih0[j + 2 * NH];
    const float hr = hp[b * H3 + j];
    const float hz = hp[b * H3 + NH + j];
    const float hn = hp[b * H3 + 2 * NH + j];
    const float h  = hprev[b * NH + j];
    const float r = 1.0f / (1.0f + expf(-(xr + hr)));
    const float z = 1.0f / (1.0f + expf(-(xz + hz)));
    const float n = tanhf(xn + r * hn);
    hnew[b * NH + j] = (1.0f - z) * n + z * h;
}

// ---------------- layer 2 gates: emits hnew[2] + fp16 copy for the MFMA GEMM --------
__global__ void k_gates_last(const float* __restrict__ xp,
                             const float* __restrict__ hp,
                             const float* __restrict__ hprev,
                             float* __restrict__ hnew,
                             _Float16* __restrict__ Xh)    // (512,256) fp16
{
    const int b = blockIdx.x;
    const int j = threadIdx.x;
    const float xr = xp[b * H3 + j];
    const float xz = xp[b * H3 + NH + j];
    const float xn = xp[b * H3 + 2 * NH + j];
    const float hr = hp[b * H3 + j];
    const float hz = hp[b * H3 + NH + j];
    const float hn = hp[b * H3 + 2 * NH + j];
    const float h  = hprev[b * NH + j];
    const float r = 1.0f / (1.0f + expf(-(xr + hr)));
    const float z = 1.0f / (1.0f + expf(-(xz + hz)));
    const float n = tanhf(xn + r * hn);
    const float v = (1.0f - z) * n + z * h;
    hnew[b * NH + j] = v;
    Xh[b * NH + j] = (_Float16)v;
}

// ---------------- small tiled fp32 GEMM:  C = A @ B.T + bias (z-batched) ----------------
// BK=64: 8 barriers per k-loop (R15-measured config).
__global__ __launch_bounds__(256)
void k_gemm_small(const float* __restrict__ A0,
                  const float* __restrict__ B0,
                  const float* __restrict__ bias0,
                  float* __restrict__ C0,
                  int M, int N, int K,
                  int sA, int sB, int sBias, int sC)
{
    constexpr int BM = 64, BN = 64, BK = 64;
    __shared__ float As[BK][BM];
    __shared__ float Bs[BK][BN];

    const float* A    = A0 + (size_t)blockIdx.z * sA;
    const float* Bm   = B0 + (size_t)blockIdx.z * sB;
    const float* bias = bias0 + (size_t)blockIdx.z * sBias;
    float*       C    = C0 + (size_t)blockIdx.z * sC;

    const int tid = threadIdx.x;
    const int tx  = tid & 15;
    const int ty  = tid >> 4;
    const int m0  = blockIdx.x * BM;
    const int n0  = blockIdx.y * BN;

    float acc[4][4];
#pragma unroll
    for (int i = 0; i < 4; i++)
#pragma unroll
        for (int j = 0; j < 4; j++) acc[i][j] = 0.0f;

    for (int k0 = 0; k0 < K; k0 += BK) {
#pragma unroll
        for (int f = 0; f < 4; f++) {
            const int fid = tid + f * 256;       // 0..1023
            const int row = fid >> 4;            // 0..63
            const int t4  = fid & 15;            // 16 float4 per 64-k row
            const int mp  = row ^ ((t4 & 3) << 3);
            {
                const float4 v = *(const float4*)(A + (size_t)(m0 + row) * K + k0 + t4 * 4);
                As[t4 * 4 + 0][mp] = v.x; As[t4 * 4 + 1][mp] = v.y;
                As[t4 * 4 + 2][mp] = v.z; As[t4 * 4 + 3][mp] = v.w;
            }
            {
                const float4 v = *(const float4*)(Bm + (size_t)(n0 + row) * K + k0 + t4 * 4);
                Bs[t4 * 4 + 0][mp] = v.x; Bs[t4 * 4 + 1][mp] = v.y;
                Bs[t4 * 4 + 2][mp] = v.z; Bs[t4 * 4 + 3][mp] = v.w;
            }
        }
        __syncthreads();
#pragma unroll
        for (int kk = 0; kk < BK; kk++) {
            const int s = ((kk >> 2) & 3) << 3;
            const float4 a0 = *(const float4*)&As[kk][(ty * 4) ^ s];
            const float4 b0 = *(const float4*)&Bs[kk][(tx * 4) ^ s];
            const float av[4] = {a0.x, a0.y, a0.z, a0.w};
            const float bv[4] = {b0.x, b0.y, b0.z, b0.w};
#pragma unroll
            for (int i = 0; i < 4; i++)
#pragma unroll
                for (int j = 0; j < 4; j++)
                    acc[i][j] = fmaf(av[i], bv[j], acc[i][j]);
        }
        __syncthreads();
    }

#pragma unroll
    for (int i = 0; i < 4; i++) {
        const size_t rowoff = (size_t)(m0 + ty * 4 + i) * N;
        const int gn = n0 + tx * 4;
        const float4 bb = *(const float4*)(bias + gn);
        float4 v;
        v.x = acc[i][0] + bb.x; v.y = acc[i][1] + bb.y;
        v.z = acc[i][2] + bb.z; v.w = acc[i][3] + bb.w;
        *(float4*)(C + rowoff + gn) = v;
    }
}

// ---------------- fused layer-1 gates + xp2 GEMM (coalesced inputs only) -------------
// A[b][j] = GRU_gate(xp1[b][j], hp1[b][j], h1[b][j]) computed inline (recomputed per
// n-block — elementwise on L2-resident data, trivial); blocks with n0==0 also write
// hnew[1]. R16-verified correct. NOTE: the MODE-0 (gather) variant was the R16 chain
// regression (12x scattered Wih0 reads) — NOT used; gather stays in k_gates0 (once).
__global__ __launch_bounds__(256)
void k_gemm_fused1(const float* __restrict__ xprev,   // (512,768) xp1
                   const float* __restrict__ hpl,     // (512,768) hp[1]
                   const float* __restrict__ hprev,   // (512,256) hidden[1]
                   const float* __restrict__ Bm,      // (768,256) WihHi[1]
                   const float* __restrict__ bias,    // (768) bih[2]
                   float* __restrict__ hnew_out,      // (512,256) hnew[1]
                   float* __restrict__ xp_out)        // (512,768) xp2
{
    constexpr int BK = 64;
    __shared__ float As[BK][64];
    __shared__ float Bs[BK][64];

    const int tid = threadIdx.x;
    const int tx  = tid & 15;
    const int ty  = tid >> 4;
    const int m0  = blockIdx.x * 64;
    const int n0  = blockIdx.y * 64;

    float acc[4][4];
#pragma unroll
    for (int i = 0; i < 4; i++)
#pragma unroll
        for (int j = 0; j < 4; j++) acc[i][j] = 0.0f;

    for (int k0 = 0; k0 < NH; k0 += BK) {
#pragma unroll
        for (int f = 0; f < 4; f++) {
            const int fid = tid + f * 256;       // 0..1023
            const int row = fid >> 4;            // 0..63
            const int t4  = fid & 15;
            const int mp  = row ^ ((t4 & 3) << 3);
            const int b   = m0 + row;
            const int j0  = k0 + t4 * 4;

            const float4 a  = *(const float4*)(xprev + (size_t)b * H3 + j0);
            const float4 c  = *(const float4*)(xprev + (size_t)b * H3 + NH + j0);
            const float4 d  = *(const float4*)(xprev + (size_t)b * H3 + 2 * NH + j0);
            const float4 hr4 = *(const float4*)(hpl + (size_t)b * H3 + j0);
            const float4 hz4 = *(const float4*)(hpl + (size_t)b * H3 + NH + j0);
            const float4 hn4 = *(const float4*)(hpl + (size_t)b * H3 + 2 * NH + j0);
            const float4 h4  = *(const float4*)(hprev + (size_t)b * NH + j0);
            const float xr[4] = {a.x, a.y, a.z, a.w};
            const float xz[4] = {c.x, c.y, c.z, c.w};
            const float xn[4] = {d.x, d.y, d.z, d.w};
            const float hr[4] = {hr4.x, hr4.y, hr4.z, hr4.w};
            const float hz[4] = {hz4.x, hz4.y, hz4.z, hz4.w};
            const float hn[4] = {hn4.x, hn4.y, hn4.z, hn4.w};
            const float hh[4] = {h4.x, h4.y, h4.z, h4.w};
            float av[4];
#pragma unroll
            for (int e = 0; e < 4; e++) {
                const float r = sigmoid_fast(xr[e] + hr[e]);
                const float z = sigmoid_fast(xz[e] + hz[e]);
                const float n = tanh_fast(xn[e] + r * hn[e]);
                av[e] = (1.0f - z) * n + z * hh[e];
            }
            As[t4 * 4 + 0][mp] = av[0]; As[t4 * 4 + 1][mp] = av[1];
            As[t4 * 4 + 2][mp] = av[2]; As[t4 * 4 + 3][mp] = av[3];
            if (n0 == 0) {
                float4 o; o.x = av[0]; o.y = av[1]; o.z = av[2]; o.w = av[3];
                *(float4*)(hnew_out + (size_t)b * NH + j0) = o;
            }
            {
                const float4 v = *(const float4*)(Bm + (size_t)(n0 + row) * NH + k0 + t4 * 4);
                Bs[t4 * 4 + 0][mp] = v.x; Bs[t4 * 4 + 1][mp] = v.y;
                Bs[t4 * 4 + 2][mp] = v.z; Bs[t4 * 4 + 3][mp] = v.w;
            }
        }
        __syncthreads();
#pragma unroll
        for (int kk = 0; kk < BK; kk++) {
            const int s = ((kk >> 2) & 3) << 3;
            const float4 a0 = *(const float4*)&As[kk][(ty * 4) ^ s];
            const float4 b0 = *(const float4*)&Bs[kk][(tx * 4) ^ s];
            const float av[4] = {a0.x, a0.y, a0.z, a0.w};
            const float bv[4] = {b0.x, b0.y, b0.z, b0.w};
#pragma unroll
            for (int i = 0; i < 4; i++)
#pragma unroll
                for (int j = 0; j < 4; j++)
                    acc[i][j] = fmaf(av[i], bv[j], acc[i][j]);
        }
        __syncthreads();
    }

#pragma unroll
    for (int i = 0; i < 4; i++) {
        const size_t rowoff = (size_t)(m0 + ty * 4 + i) * H3;
        const int gn = n0 + tx * 4;
        const float4 bb = *(const float4*)(bias + gn);
        float4 v;
        v.x = acc[i][0] + bb.x; v.y = acc[i][1] + bb.y;
        v.z = acc[i][2] + bb.z; v.w = acc[i][3] + bb.w;
        *(float4*)(xp_out + rowoff + gn) = v;
    }
}

// ---------------- output projection: act = tanh(x @ Wout.T + bout), fp16 MFMA ----------
// EXACT R15 kernel (measured: total 148.3us, out ~103us). R16's 2nx4m wave split
// REGRESSED (doubled per-wave X loads + 2 shared wf registers serialized the MFMA
// chains -> latency-exposed) — reverted.
// ALLOCATOR MODEL (R7..R16): launch_bounds caps ARCH VGPRs at ~256/minW; MFMA acc
// lives in AGPRs ON TOP. (512,4): 64 arch + 64 agpr = 128/wave -> 2 blocks/CU, no
// spill. Structure: BM=512 (whole batch), BN=64/block -> W fetched exactly once; full
// K=256 W panel (64KB fp32) staged via global_load_lds (1KB rows, src-side 16B-chunk
// XOR swizzle); K-loop barrier-free (cvt fp32->fp16 on LDS read, 4 independent wf
// chains); epilogue = 2 passes x 256 rows through the freed buffer -> 256B-contiguous
// NONTEMPORAL stores (R15 win: C is write-once, bypass L2).
// mfma(A=W, B=X): D row((lane>>4)*4+reg)=n, col(lane&15)=m (verified r1-r16).
__global__ __launch_bounds__(512, 4)
void k_out_mfma(const _Float16* __restrict__ Xh,  // (512,256) fp16
                const float* __restrict__ W,      // (NI,256) fp32
                const float* __restrict__ bout,   // (NI)
                float* __restrict__ C)            // (512,NI)
{
    __shared__ __align__(16) float S[16384];   // 64 KB: W panel, then C half-tiles

    const int n0   = blockIdx.x * 64;          // n-tile base (1563 tiles)
    const int tid  = threadIdx.x;
    const int w    = tid >> 6;                 // wave 0..7 -> m rows [w*64, w*64+64)
    const int lane = tid & 63;
    const int lr   = lane & 15;
    const int lg   = lane >> 4;                // 0..3

    // ---- stage W panel: 64 rows x 64 16B-chunks; each wave-instr = one full 1KB row ----
#pragma unroll
    for (int it = 0; it < 8; ++it) {
        const int fid = it * 512 + tid;        // chunk id 0..4095
        const int row = fid >> 6;              // 0..63
        const int p   = fid & 63;              // physical chunk in LDS row
        int gr = n0 + row; if (gr >= NI) gr = NI - 1;      // clamp; cols masked later
        const float* src = W + (size_t)gr * NH + (size_t)(p ^ (row & 7)) * 4;
        __builtin_amdgcn_global_load_lds(
            (const __attribute__((address_space(1))) void*)src,
            (__attribute__((address_space(3))) void*)(S + fid * 4),
            16, 0, 0);
    }

    f32x4 acc[4][4];
#pragma unroll
    for (int nf = 0; nf < 4; ++nf)
#pragma unroll
        for (int mf = 0; mf < 4; ++mf) acc[nf][mf] = (f32x4){0.f, 0.f, 0.f, 0.f};

    __syncthreads();

    const _Float16* xbase = Xh + (size_t)(w * 64 + lr) * NH + lg * 8;

    // ---- K-loop: 8 steps, no barriers; W frags from LDS (cvt), X frags from L2 ----
#pragma unroll
    for (int t = 0; t < 8; ++t) {
        f16x8 xf[4];
#pragma unroll
        for (int mf = 0; mf < 4; ++mf)
            xf[mf] = *(const f16x8*)(xbase + mf * 16 * NH + t * 32);
#pragma unroll
        for (int nf = 0; nf < 4; ++nf) {
            const int rl = nf * 16 + lr;                      // W-panel row 0..63
            const int c0 = t * 8 + ((lg * 2)     ^ (rl & 7)); // phys chunk (undo swizzle)
            const int c1 = t * 8 + ((lg * 2 + 1) ^ (rl & 7));
            const f32x4 u0 = *(const f32x4*)(S + rl * 256 + c0 * 4);
            const f32x4 u1 = *(const f32x4*)(S + rl * 256 + c1 * 4);
            f16x8 h;
            h[0] = (_Float16)u0[0]; h[1] = (_Float16)u0[1];
            h[2] = (_Float16)u0[2]; h[3] = (_Float16)u0[3];
            h[4] = (_Float16)u1[0]; h[5] = (_Float16)u1[1];
            h[6] = (_Float16)u1[2]; h[7] = (_Float16)u1[3];
#pragma unroll
            for (int mf = 0; mf < 4; ++mf)
                acc[nf][mf] = __builtin_amdgcn_mfma_f32_16x16x32_f16(
                    h, xf[mf], acc[nf][mf], 0, 0, 0);
        }
    }

    // ---- epilogue: 2 passes (256 rows each) via LDS; 256B-contiguous NT stores ----
#pragma unroll
    for (int pass = 0; pass < 2; ++pass) {
        __syncthreads();                       // pass 0: all k-loop LDS reads done
        if ((w >> 2) == pass) {
            const int mloc = (w & 3) * 64;
#pragma unroll
            for (int nf = 0; nf < 4; ++nf) {
                const int gn = n0 + nf * 16 + lg * 4;
                const float4 bb = (gn < NI) ? *(const float4*)(bout + gn)
                                            : make_float4(0.f, 0.f, 0.f, 0.f);
#pragma unroll
                for (int mf = 0; mf < 4; ++mf) {
                    const int mr = mloc + mf * 16 + lr;       // 0..255
                    const int p  = (nf * 4 + lg) ^ (lr & 7);  // swizzled float4 slot
                    float4 v;
                    v.x = tanh_fast(acc[nf][mf][0] + bb.x);
                    v.y = tanh_fast(acc[nf][mf][1] + bb.y);
                    v.z = tanh_fast(acc[nf][mf][2] + bb.z);
                    v.w = tanh_fast(acc[nf][mf][3] + bb.w);
                    *(float4*)(S + mr * 64 + p * 4) = v;
                }
            }
        }
        __syncthreads();
#pragma unroll
        for (int it = 0; it < 8; ++it) {
            const int fid = it * 512 + tid;    // 0..4095
            const int row = fid >> 4;          // 0..255
            const int c   = fid & 15;          // logical float4 chunk
            const int gn  = n0 + c * 4;
            if (gn < NI) {
                const f32x4 v = *(const f32x4*)(S + row * 64 + ((c ^ (row & 7)) * 4));
                __builtin_nontemporal_store(
                    v, (f32x4*)(C + (size_t)(pass * 256 + row) * NI + gn));
            }
        }
    }
}

extern "C" void kernel_launch(void* const* d_in, const int* in_sizes, int n_in,
                              void* d_out, int out_size, void* d_ws, size_t ws_size,
                              hipStream_t stream)
{
    const int*   idx    = (const int*)  d_in[0];
    const float* hidden = (const float*)d_in[1];   // (3,512,256)
    const float* Wih0   = (const float*)d_in[2];   // (768,100000)
    const float* WihHi  = (const float*)d_in[3];   // (2,768,256)
    const float* Whh    = (const float*)d_in[4];   // (3,768,256)
    const float* bih    = (const float*)d_in[5];   // (3,768)
    const float* bhh    = (const float*)d_in[6];   // (3,768)
    const float* Wout   = (const float*)d_in[7];   // (100000,256)
    const float* bout   = (const float*)d_in[8];   // (100000)

    float* act  = (float*)d_out;                  // (512, NI)
    float* hnew = act + (size_t)NB * NI;          // (3,512,256)
    // fp32 scratch lives in the activation region; final GEMM overwrites it.
    float* hp  = act;                             // (3,512,768)
    float* xp1 = act + 3 * NB * H3;               // (512,768)
    float* xp2 = xp1 + NB * H3;                   // (512,768)
    // fp16 X lives in d_ws (must survive while the big GEMM writes act)
    _Float16* Xh = (_Float16*)d_ws;               // (512,256) = 256 KB

    const dim3 bs(256);
    const dim3 gs_hp(NB / 64, H3 / 64, 3);
    const dim3 gs_xp(NB / 64, H3 / 64, 1);

    // ---- all hidden-projections (depend only on input `hidden`) ----
    k_gemm_small<<<gs_hp, bs, 0, stream>>>(hidden, Whh, bhh, hp,
                                           NB, H3, NH, NB * NH, H3 * NH, H3, NB * H3);
    // ---- layer 0 (x_proj gathered inline, ONCE) ----
    k_gates0<<<NB, bs, 0, stream>>>(idx, Wih0, bih, hp, hidden, hnew);
    // ---- layer 1 x-projection ----
    k_gemm_small<<<gs_xp, bs, 0, stream>>>(hnew, WihHi, bih + H3, xp1,
                                           NB, H3, NH, 0, 0, 0, 0);
    // ---- layer-1 gates fused into layer-2 x-projection (writes hnew[1] + xp2) ----
    k_gemm_fused1<<<gs_xp, bs, 0, stream>>>(xp1, hp + NB * H3, hidden + NB * NH,
                                            WihHi + H3 * NH, bih + 2 * H3,
                                            hnew + NB * NH, xp2);
    // ---- layer 2 gates (hnew[2] + fp16 Xh) ----
    k_gates_last<<<NB, bs, 0, stream>>>(xp2, hp + 2 * NB * H3, hidden + 2 * NB * NH,
                                        hnew + 2 * NB * NH, Xh);
    // ---- output projection: 1563 n-tiles of 64, whole batch per block ----
    k_out_mfma<<<dim3((NI + 63) / 64), dim3(512), 0, stream>>>(Xh, Wout, bout, act);
}

// Round 18
// 148.276 us; speedup vs baseline: 1.6961x; 1.0472x over previous
//
#include <hip/hip_runtime.h>
#include <math.h>
#include <stdint.h>

#define NI 100000   // N_ITEMS
#define NB 512      // batch
#define NH 256      // hidden H
#define H3 768      // 3*H

typedef _Float16 f16x8 __attribute__((ext_vector_type(8)));
typedef float    f32x4 __attribute__((ext_vector_type(4)));

__device__ __forceinline__ float tanh_fast(float x) {
    x = fminf(fmaxf(x, -9.0f), 9.0f);
    const float e = __expf(2.0f * x);
    return (e - 1.0f) * __builtin_amdgcn_rcpf(e + 1.0f);
}
__device__ __forceinline__ float sigmoid_fast(float x) {
    return 1.0f / (1.0f + __expf(-x));
}

// ---------------- GRU gate elementwise (layer 0: gather x_proj inline) ----------------
__global__ void k_gates0(const int* __restrict__ idx,
                         const float* __restrict__ Wih0,   // (768, NI)
                         const float* __restrict__ bih0,   // (768)
                         const float* __restrict__ hp,     // (512,768)
                         const float* __restrict__ hprev,  // (512,256)
                         float* __restrict__ hnew)         // (512,256)
{
    const int b = blockIdx.x;
    const int j = threadIdx.x;          // 0..255
    const int ib = idx[b];
    const float xr = Wih0[(size_t)(j          ) * NI + ib] + bih0[j];
    const float xz = Wih0[(size_t)(j + NH     ) * NI + ib] + bih0[j + NH];
    const float xn = Wih0[(size_t)(j + 2 * NH ) * NI + ib] + bih0[j + 2 * NH];
    const float hr = hp[b * H3 + j];
    const float hz = hp[b * H3 + NH + j];
    const float hn = hp[b * H3 + 2 * NH + j];
    const float h  = hprev[b * NH + j];
    const float r = sigmoid_fast(xr + hr);
    const float z = sigmoid_fast(xz + hz);
    const float n = tanh_fast(xn + r * hn);
    hnew[b * NH + j] = (1.0f - z) * n + z * h;
}

// ---------------- GRU gate elementwise (layer 1) ----------------
__global__ void k_gates(const float* __restrict__ xp,
                        const float* __restrict__ hp,
                        const float* __restrict__ hprev,
                        float* __restrict__ hnew)
{
    const int b = blockIdx.x;
    const int j = threadIdx.x;
    const float xr = xp[b * H3 + j];
    const float xz = xp[b * H3 + NH + j];
    const float xn = xp[b * H3 + 2 * NH + j];
    const float hr = hp[b * H3 + j];
    const float hz = hp[b * H3 + NH + j];
    const float hn = hp[b * H3 + 2 * NH + j];
    const float h  = hprev[b * NH + j];
    const float r = sigmoid_fast(xr + hr);
    const float z = sigmoid_fast(xz + hz);
    const float n = tanh_fast(xn + r * hn);
    hnew[b * NH + j] = (1.0f - z) * n + z * h;
}

// ---------------- layer 2 gates: also emit fp16 copy of h2 for the MFMA GEMM --------
__global__ void k_gates_last(const float* __restrict__ xp,
                             const float* __restrict__ hp,
                             const float* __restrict__ hprev,
                             float* __restrict__ hnew,
                             _Float16* __restrict__ Xh)    // (512,256) fp16
{
    const int b = blockIdx.x;
    const int j = threadIdx.x;
    const float xr = xp[b * H3 + j];
    const float xz = xp[b * H3 + NH + j];
    const float xn = xp[b * H3 + 2 * NH + j];
    const float hr = hp[b * H3 + j];
    const float hz = hp[b * H3 + NH + j];
    const float hn = hp[b * H3 + 2 * NH + j];
    const float h  = hprev[b * NH + j];
    const float r = sigmoid_fast(xr + hr);
    const float z = sigmoid_fast(xz + hz);
    const float n = tanh_fast(xn + r * hn);
    const float v = (1.0f - z) * n + z * h;
    hnew[b * NH + j] = v;
    Xh[b * NH + j] = (_Float16)v;
}

// ---------------- small tiled fp32 GEMM:  C = A @ B.T + bias (z-batched) ----------------
// BK=64: 8 barriers per k-loop (R15-measured config).
__global__ __launch_bounds__(256)
void k_gemm_small(const float* __restrict__ A0,
                  const float* __restrict__ B0,
                  const float* __restrict__ bias0,
                  float* __restrict__ C0,
                  int M, int N, int K,
                  int sA, int sB, int sBias, int sC)
{
    constexpr int BM = 64, BN = 64, BK = 64;
    __shared__ float As[BK][BM];
    __shared__ float Bs[BK][BN];

    const float* A    = A0 + (size_t)blockIdx.z * sA;
    const float* Bm   = B0 + (size_t)blockIdx.z * sB;
    const float* bias = bias0 + (size_t)blockIdx.z * sBias;
    float*       C    = C0 + (size_t)blockIdx.z * sC;

    const int tid = threadIdx.x;
    const int tx  = tid & 15;
    const int ty  = tid >> 4;
    const int m0  = blockIdx.x * BM;
    const int n0  = blockIdx.y * BN;

    float acc[4][4];
#pragma unroll
    for (int i = 0; i < 4; i++)
#pragma unroll
        for (int j = 0; j < 4; j++) acc[i][j] = 0.0f;

    for (int k0 = 0; k0 < K; k0 += BK) {
#pragma unroll
        for (int f = 0; f < 4; f++) {
            const int fid = tid + f * 256;       // 0..1023
            const int row = fid >> 4;            // 0..63
            const int t4  = fid & 15;            // 16 float4 per 64-k row
            const int mp  = row ^ ((t4 & 3) << 3);
            {
                const float4 v = *(const float4*)(A + (size_t)(m0 + row) * K + k0 + t4 * 4);
                As[t4 * 4 + 0][mp] = v.x; As[t4 * 4 + 1][mp] = v.y;
                As[t4 * 4 + 2][mp] = v.z; As[t4 * 4 + 3][mp] = v.w;
            }
            {
                const float4 v = *(const float4*)(Bm + (size_t)(n0 + row) * K + k0 + t4 * 4);
                Bs[t4 * 4 + 0][mp] = v.x; Bs[t4 * 4 + 1][mp] = v.y;
                Bs[t4 * 4 + 2][mp] = v.z; Bs[t4 * 4 + 3][mp] = v.w;
            }
        }
        __syncthreads();
#pragma unroll
        for (int kk = 0; kk < BK; kk++) {
            const int s = ((kk >> 2) & 3) << 3;
            const float4 a0 = *(const float4*)&As[kk][(ty * 4) ^ s];
            const float4 b0 = *(const float4*)&Bs[kk][(tx * 4) ^ s];
            const float av[4] = {a0.x, a0.y, a0.z, a0.w};
            const float bv[4] = {b0.x, b0.y, b0.z, b0.w};
#pragma unroll
            for (int i = 0; i < 4; i++)
#pragma unroll
                for (int j = 0; j < 4; j++)
                    acc[i][j] = fmaf(av[i], bv[j], acc[i][j]);
        }
        __syncthreads();
    }

#pragma unroll
    for (int i = 0; i < 4; i++) {
        const size_t rowoff = (size_t)(m0 + ty * 4 + i) * N;
        const int gn = n0 + tx * 4;
        const float4 bb = *(const float4*)(bias + gn);
        float4 v;
        v.x = acc[i][0] + bb.x; v.y = acc[i][1] + bb.y;
        v.z = acc[i][2] + bb.z; v.w = acc[i][3] + bb.w;
        *(float4*)(C + rowoff + gn) = v;
    }
}

// ---------------- output projection: act = tanh(x @ Wout.T + bout), fp16 MFMA ----------
// EXACT R15 kernel (best measured: total 148.3us, out ~103us).
// ALLOCATOR MODEL (R7..R17): launch_bounds caps ARCH VGPRs at ~256/minW; MFMA acc
// lives in AGPRs ON TOP. (512,4): 64 arch + 64 agpr = 128/wave -> 2 blocks/CU, no
// spill. Structure: BM=512 (whole batch), BN=64/block -> W fetched exactly once; full
// K=256 W panel (64KB fp32) staged via global_load_lds (1KB rows, src-side 16B-chunk
// XOR swizzle); K-loop barrier-free (cvt fp32->fp16 on LDS read, 4 independent wf
// chains); epilogue = 2 passes x 256 rows through the freed buffer -> 256B-contiguous
// NONTEMPORAL stores (C is write-once, bypass L2).
// mfma(A=W, B=X): D row((lane>>4)*4+reg)=n, col(lane&15)=m (verified r1-r17).
// REJECTED variants (measured): 2nx4m wave split (R16, +78us), multi-tile pipeline
// (R9-R13, all slower), fp16 reg-staging (spills at any minW>=3), minW=2 (1 blk/CU).
__global__ __launch_bounds__(512, 4)
void k_out_mfma(const _Float16* __restrict__ Xh,  // (512,256) fp16
                const float* __restrict__ W,      // (NI,256) fp32
                const float* __restrict__ bout,   // (NI)
                float* __restrict__ C)            // (512,NI)
{
    __shared__ __align__(16) float S[16384];   // 64 KB: W panel, then C half-tiles

    const int n0   = blockIdx.x * 64;          // n-tile base (1563 tiles)
    const int tid  = threadIdx.x;
    const int w    = tid >> 6;                 // wave 0..7 -> m rows [w*64, w*64+64)
    const int lane = tid & 63;
    const int lr   = lane & 15;
    const int lg   = lane >> 4;                // 0..3

    // ---- stage W panel: 64 rows x 64 16B-chunks; each wave-instr = one full 1KB row ----
#pragma unroll
    for (int it = 0; it < 8; ++it) {
        const int fid = it * 512 + tid;        // chunk id 0..4095
        const int row = fid >> 6;              // 0..63
        const int p   = fid & 63;              // physical chunk in LDS row
        int gr = n0 + row; if (gr >= NI) gr = NI - 1;      // clamp; cols masked later
        const float* src = W + (size_t)gr * NH + (size_t)(p ^ (row & 7)) * 4;
        __builtin_amdgcn_global_load_lds(
            (const __attribute__((address_space(1))) void*)src,
            (__attribute__((address_space(3))) void*)(S + fid * 4),
            16, 0, 0);
    }

    f32x4 acc[4][4];
#pragma unroll
    for (int nf = 0; nf < 4; ++nf)
#pragma unroll
        for (int mf = 0; mf < 4; ++mf) acc[nf][mf] = (f32x4){0.f, 0.f, 0.f, 0.f};

    __syncthreads();

    const _Float16* xbase = Xh + (size_t)(w * 64 + lr) * NH + lg * 8;

    // ---- K-loop: 8 steps, no barriers; W frags from LDS (cvt), X frags from L2 ----
#pragma unroll
    for (int t = 0; t < 8; ++t) {
        f16x8 xf[4];
#pragma unroll
        for (int mf = 0; mf < 4; ++mf)
            xf[mf] = *(const f16x8*)(xbase + mf * 16 * NH + t * 32);
#pragma unroll
        for (int nf = 0; nf < 4; ++nf) {
            const int rl = nf * 16 + lr;                      // W-panel row 0..63
            const int c0 = t * 8 + ((lg * 2)     ^ (rl & 7)); // phys chunk (undo swizzle)
            const int c1 = t * 8 + ((lg * 2 + 1) ^ (rl & 7));
            const f32x4 u0 = *(const f32x4*)(S + rl * 256 + c0 * 4);
            const f32x4 u1 = *(const f32x4*)(S + rl * 256 + c1 * 4);
            f16x8 h;
            h[0] = (_Float16)u0[0]; h[1] = (_Float16)u0[1];
            h[2] = (_Float16)u0[2]; h[3] = (_Float16)u0[3];
            h[4] = (_Float16)u1[0]; h[5] = (_Float16)u1[1];
            h[6] = (_Float16)u1[2]; h[7] = (_Float16)u1[3];
#pragma unroll
            for (int mf = 0; mf < 4; ++mf)
                acc[nf][mf] = __builtin_amdgcn_mfma_f32_16x16x32_f16(
                    h, xf[mf], acc[nf][mf], 0, 0, 0);
        }
    }

    // ---- epilogue: 2 passes (256 rows each) via LDS; 256B-contiguous NT stores ----
#pragma unroll
    for (int pass = 0; pass < 2; ++pass) {
        __syncthreads();                       // pass 0: all k-loop LDS reads done
        if ((w >> 2) == pass) {
            const int mloc = (w & 3) * 64;
#pragma unroll
            for (int nf = 0; nf < 4; ++nf) {
                const int gn = n0 + nf * 16 + lg * 4;
                const float4 bb = (gn < NI) ? *(const float4*)(bout + gn)
                                            : make_float4(0.f, 0.f, 0.f, 0.f);
#pragma unroll
                for (int mf = 0; mf < 4; ++mf) {
                    const int mr = mloc + mf * 16 + lr;       // 0..255
                    const int p  = (nf * 4 + lg) ^ (lr & 7);  // swizzled float4 slot
                    float4 v;
                    v.x = tanh_fast(acc[nf][mf][0] + bb.x);
                    v.y = tanh_fast(acc[nf][mf][1] + bb.y);
                    v.z = tanh_fast(acc[nf][mf][2] + bb.z);
                    v.w = tanh_fast(acc[nf][mf][3] + bb.w);
                    *(float4*)(S + mr * 64 + p * 4) = v;
                }
            }
        }
        __syncthreads();
#pragma unroll
        for (int it = 0; it < 8; ++it) {
            const int fid = it * 512 + tid;    // 0..4095
            const int row = fid >> 4;          // 0..255
            const int c   = fid & 15;          // logical float4 chunk
            const int gn  = n0 + c * 4;
            if (gn < NI) {
                const f32x4 v = *(const f32x4*)(S + row * 64 + ((c ^ (row & 7)) * 4));
                __builtin_nontemporal_store(
                    v, (f32x4*)(C + (size_t)(pass * 256 + row) * NI + gn));
            }
        }
    }
}

extern "C" void kernel_launch(void* const* d_in, const int* in_sizes, int n_in,
                              void* d_out, int out_size, void* d_ws, size_t ws_size,
                              hipStream_t stream)
{
    const int*   idx    = (const int*)  d_in[0];
    const float* hidden = (const float*)d_in[1];   // (3,512,256)
    const float* Wih0   = (const float*)d_in[2];   // (768,100000)
    const float* WihHi  = (const float*)d_in[3];   // (2,768,256)
    const float* Whh    = (const float*)d_in[4];   // (3,768,256)
    const float* bih    = (const float*)d_in[5];   // (3,768)
    const float* bhh    = (const float*)d_in[6];   // (3,768)
    const float* Wout   = (const float*)d_in[7];   // (100000,256)
    const float* bout   = (const float*)d_in[8];   // (100000)

    float* act  = (float*)d_out;                  // (512, NI)
    float* hnew = act + (size_t)NB * NI;          // (3,512,256)
    // fp32 scratch lives in the activation region; final GEMM overwrites it.
    float* hp = act;                              // (3,512,768)
    float* xp = act + 3 * NB * H3;                // (512,768)
    // fp16 X lives in d_ws (must survive while the big GEMM writes act)
    _Float16* Xh = (_Float16*)d_ws;               // (512,256) = 256 KB

    const dim3 bs(256);
    const dim3 gs_hp(NB / 64, H3 / 64, 3);
    const dim3 gs_xp(NB / 64, H3 / 64, 1);

    // ---- all hidden-projections (depend only on input `hidden`) ----
    k_gemm_small<<<gs_hp, bs, 0, stream>>>(hidden, Whh, bhh, hp,
                                           NB, H3, NH, NB * NH, H3 * NH, H3, NB * H3);
    // ---- layer 0 (x_proj gathered inline) ----
    k_gates0<<<NB, bs, 0, stream>>>(idx, Wih0, bih, hp, hidden, hnew);
    // ---- layer 1 ----
    k_gemm_small<<<gs_xp, bs, 0, stream>>>(hnew, WihHi, bih + H3, xp,
                                           NB, H3, NH, 0, 0, 0, 0);
    k_gates<<<NB, bs, 0, stream>>>(xp, hp + NB * H3, hidden + NB * NH, hnew + NB * NH);
    // ---- layer 2 (also emits fp16 h2) ----
    k_gemm_small<<<gs_xp, bs, 0, stream>>>(hnew + NB * NH, WihHi + H3 * NH, bih + 2 * H3, xp,
                                           NB, H3, NH, 0, 0, 0, 0);
    k_gates_last<<<NB, bs, 0, stream>>>(xp, hp + 2 * NB * H3, hidden + 2 * NB * NH,
                                        hnew + 2 * NB * NH, Xh);

    // ---- output projection: 1563 n-tiles of 64, whole batch per block ----
    k_out_mfma<<<dim3((NI + 63) / 64), dim3(512), 0, stream>>>(Xh, Wout, bout, act);
}

// Round 19
// 147.243 us; speedup vs baseline: 1.7080x; 1.0070x over previous
//
#include <hip/hip_runtime.h>
#include <math.h>
#include <stdint.h>

#define NI 100000   // N_ITEMS
#define NB 512      // batch
#define NH 256      // hidden H
#define H3 768      // 3*H

typedef _Float16 f16x8 __attribute__((ext_vector_type(8)));
typedef float    f32x4 __attribute__((ext_vector_type(4)));

// Raw workgroup barrier that orders LDS (lgkmcnt) but does NOT drain vmcnt:
// outstanding nontemporal global stores stay in flight across it.
// sched_barrier(0) fences compiler motion around the asm waitcnt (rule #18).
#define RAW_LDS_BARRIER() do {                                   \
    asm volatile("s_waitcnt lgkmcnt(0)" ::: "memory");           \
    __builtin_amdgcn_sched_barrier(0);                           \
    __builtin_amdgcn_s_barrier();                                \
    __builtin_amdgcn_sched_barrier(0);                           \
} while (0)

__device__ __forceinline__ float tanh_fast(float x) {
    x = fminf(fmaxf(x, -9.0f), 9.0f);
    const float e = __expf(2.0f * x);
    return (e - 1.0f) * __builtin_amdgcn_rcpf(e + 1.0f);
}
__device__ __forceinline__ float sigmoid_fast(float x) {
    return 1.0f / (1.0f + __expf(-x));
}

// ---------------- GRU gate elementwise (layer 0: gather x_proj inline) ----------------
__global__ void k_gates0(const int* __restrict__ idx,
                         const float* __restrict__ Wih0,   // (768, NI)
                         const float* __restrict__ bih0,   // (768)
                         const float* __restrict__ hp,     // (512,768)
                         const float* __restrict__ hprev,  // (512,256)
                         float* __restrict__ hnew)         // (512,256)
{
    const int b = blockIdx.x;
    const int j = threadIdx.x;          // 0..255
    const int ib = idx[b];
    const float xr = Wih0[(size_t)(j          ) * NI + ib] + bih0[j];
    const float xz = Wih0[(size_t)(j + NH     ) * NI + ib] + bih0[j + NH];
    const float xn = Wih0[(size_t)(j + 2 * NH ) * NI + ib] + bih0[j + 2 * NH];
    const float hr = hp[b * H3 + j];
    const float hz = hp[b * H3 + NH + j];
    const float hn = hp[b * H3 + 2 * NH + j];
    const float h  = hprev[b * NH + j];
    const float r = sigmoid_fast(xr + hr);
    const float z = sigmoid_fast(xz + hz);
    const float n = tanh_fast(xn + r * hn);
    hnew[b * NH + j] = (1.0f - z) * n + z * h;
}

// ---------------- GRU gate elementwise (layer 1) ----------------
__global__ void k_gates(const float* __restrict__ xp,
                        const float* __restrict__ hp,
                        const float* __restrict__ hprev,
                        float* __restrict__ hnew)
{
    const int b = blockIdx.x;
    const int j = threadIdx.x;
    const float xr = xp[b * H3 + j];
    const float xz = xp[b * H3 + NH + j];
    const float xn = xp[b * H3 + 2 * NH + j];
    const float hr = hp[b * H3 + j];
    const float hz = hp[b * H3 + NH + j];
    const float hn = hp[b * H3 + 2 * NH + j];
    const float h  = hprev[b * NH + j];
    const float r = sigmoid_fast(xr + hr);
    const float z = sigmoid_fast(xz + hz);
    const float n = tanh_fast(xn + r * hn);
    hnew[b * NH + j] = (1.0f - z) * n + z * h;
}

// ---------------- layer 2 gates: also emit fp16 copy of h2 for the MFMA GEMM --------
__global__ void k_gates_last(const float* __restrict__ xp,
                             const float* __restrict__ hp,
                             const float* __restrict__ hprev,
                             float* __restrict__ hnew,
                             _Float16* __restrict__ Xh)    // (512,256) fp16
{
    const int b = blockIdx.x;
    const int j = threadIdx.x;
    const float xr = xp[b * H3 + j];
    const float xz = xp[b * H3 + NH + j];
    const float xn = xp[b * H3 + 2 * NH + j];
    const float hr = hp[b * H3 + j];
    const float hz = hp[b * H3 + NH + j];
    const float hn = hp[b * H3 + 2 * NH + j];
    const float h  = hprev[b * NH + j];
    const float r = sigmoid_fast(xr + hr);
    const float z = sigmoid_fast(xz + hz);
    const float n = tanh_fast(xn + r * hn);
    const float v = (1.0f - z) * n + z * h;
    hnew[b * NH + j] = v;
    Xh[b * NH + j] = (_Float16)v;
}

// ---------------- small tiled fp32 GEMM:  C = A @ B.T + bias (z-batched) ----------------
// BK=64: 8 barriers per k-loop (R15-measured config).
__global__ __launch_bounds__(256)
void k_gemm_small(const float* __restrict__ A0,
                  const float* __restrict__ B0,
                  const float* __restrict__ bias0,
                  float* __restrict__ C0,
                  int M, int N, int K,
                  int sA, int sB, int sBias, int sC)
{
    constexpr int BM = 64, BN = 64, BK = 64;
    __shared__ float As[BK][BM];
    __shared__ float Bs[BK][BN];

    const float* A    = A0 + (size_t)blockIdx.z * sA;
    const float* Bm   = B0 + (size_t)blockIdx.z * sB;
    const float* bias = bias0 + (size_t)blockIdx.z * sBias;
    float*       C    = C0 + (size_t)blockIdx.z * sC;

    const int tid = threadIdx.x;
    const int tx  = tid & 15;
    const int ty  = tid >> 4;
    const int m0  = blockIdx.x * BM;
    const int n0  = blockIdx.y * BN;

    float acc[4][4];
#pragma unroll
    for (int i = 0; i < 4; i++)
#pragma unroll
        for (int j = 0; j < 4; j++) acc[i][j] = 0.0f;

    for (int k0 = 0; k0 < K; k0 += BK) {
#pragma unroll
        for (int f = 0; f < 4; f++) {
            const int fid = tid + f * 256;       // 0..1023
            const int row = fid >> 4;            // 0..63
            const int t4  = fid & 15;            // 16 float4 per 64-k row
            const int mp  = row ^ ((t4 & 3) << 3);
            {
                const float4 v = *(const float4*)(A + (size_t)(m0 + row) * K + k0 + t4 * 4);
                As[t4 * 4 + 0][mp] = v.x; As[t4 * 4 + 1][mp] = v.y;
                As[t4 * 4 + 2][mp] = v.z; As[t4 * 4 + 3][mp] = v.w;
            }
            {
                const float4 v = *(const float4*)(Bm + (size_t)(n0 + row) * K + k0 + t4 * 4);
                Bs[t4 * 4 + 0][mp] = v.x; Bs[t4 * 4 + 1][mp] = v.y;
                Bs[t4 * 4 + 2][mp] = v.z; Bs[t4 * 4 + 3][mp] = v.w;
            }
        }
        __syncthreads();
#pragma unroll
        for (int kk = 0; kk < BK; kk++) {
            const int s = ((kk >> 2) & 3) << 3;
            const float4 a0 = *(const float4*)&As[kk][(ty * 4) ^ s];
            const float4 b0 = *(const float4*)&Bs[kk][(tx * 4) ^ s];
            const float av[4] = {a0.x, a0.y, a0.z, a0.w};
            const float bv[4] = {b0.x, b0.y, b0.z, b0.w};
#pragma unroll
            for (int i = 0; i < 4; i++)
#pragma unroll
                for (int j = 0; j < 4; j++)
                    acc[i][j] = fmaf(av[i], bv[j], acc[i][j]);
        }
        __syncthreads();
    }

#pragma unroll
    for (int i = 0; i < 4; i++) {
        const size_t rowoff = (size_t)(m0 + ty * 4 + i) * N;
        const int gn = n0 + tx * 4;
        const float4 bb = *(const float4*)(bias + gn);
        float4 v;
        v.x = acc[i][0] + bb.x; v.y = acc[i][1] + bb.y;
        v.z = acc[i][2] + bb.z; v.w = acc[i][3] + bb.w;
        *(float4*)(C + rowoff + gn) = v;
    }
}

// ---------------- output projection: act = tanh(x @ Wout.T + bout), fp16 MFMA ----------
// R19 = R15/R18 kernel (148.3us stable) with ONE change: the epilogue's
// __syncthreads() replaced by RAW_LDS_BARRIER (s_barrier + lgkmcnt-only wait).
// __syncthreads drains vmcnt(0), which includes the just-issued NT global stores —
// each block was waiting ~2-5us TWICE for its 64KB store bursts to reach HBM before
// reusing the LDS. The actual LDS hazard only needs lgkmcnt (ds_reads feeding the
// stores complete long before the stores land). NT stores now drain in background
// across the pass boundary / at endpgm.
// ALLOCATOR MODEL (R7..R18): launch_bounds caps ARCH VGPRs at ~256/minW; MFMA acc
// lives in AGPRs ON TOP. (512,4): 64 arch + 64 agpr = 128/wave -> 2 blocks/CU, no
// spill. Structure: BM=512 (whole batch), BN=64/block -> W fetched exactly once; full
// K=256 W panel (64KB fp32) staged via global_load_lds (1KB rows, src-side 16B-chunk
// XOR swizzle; stage barrier stays __syncthreads for vmcnt); K-loop barrier-free;
// epilogue = 2 passes x 256 rows through the freed buffer -> 256B-contiguous NT stores.
// mfma(A=W, B=X): D row((lane>>4)*4+reg)=n, col(lane&15)=m (verified r1-r18).
__global__ __launch_bounds__(512, 4)
void k_out_mfma(const _Float16* __restrict__ Xh,  // (512,256) fp16
                const float* __restrict__ W,      // (NI,256) fp32
                const float* __restrict__ bout,   // (NI)
                float* __restrict__ C)            // (512,NI)
{
    __shared__ __align__(16) float S[16384];   // 64 KB: W panel, then C half-tiles

    const int n0   = blockIdx.x * 64;          // n-tile base (1563 tiles)
    const int tid  = threadIdx.x;
    const int w    = tid >> 6;                 // wave 0..7 -> m rows [w*64, w*64+64)
    const int lane = tid & 63;
    const int lr   = lane & 15;
    const int lg   = lane >> 4;                // 0..3

    // ---- stage W panel: 64 rows x 64 16B-chunks; each wave-instr = one full 1KB row ----
#pragma unroll
    for (int it = 0; it < 8; ++it) {
        const int fid = it * 512 + tid;        // chunk id 0..4095
        const int row = fid >> 6;              // 0..63
        const int p   = fid & 63;              // physical chunk in LDS row
        int gr = n0 + row; if (gr >= NI) gr = NI - 1;      // clamp; cols masked later
        const float* src = W + (size_t)gr * NH + (size_t)(p ^ (row & 7)) * 4;
        __builtin_amdgcn_global_load_lds(
            (const __attribute__((address_space(1))) void*)src,
            (__attribute__((address_space(3))) void*)(S + fid * 4),
            16, 0, 0);
    }

    f32x4 acc[4][4];
#pragma unroll
    for (int nf = 0; nf < 4; ++nf)
#pragma unroll
        for (int mf = 0; mf < 4; ++mf) acc[nf][mf] = (f32x4){0.f, 0.f, 0.f, 0.f};

    __syncthreads();                           // stage uses vmcnt -> full drain needed

    const _Float16* xbase = Xh + (size_t)(w * 64 + lr) * NH + lg * 8;

    // ---- K-loop: 8 steps, no barriers; W frags from LDS (cvt), X frags from L2 ----
#pragma unroll
    for (int t = 0; t < 8; ++t) {
        f16x8 xf[4];
#pragma unroll
        for (int mf = 0; mf < 4; ++mf)
            xf[mf] = *(const f16x8*)(xbase + mf * 16 * NH + t * 32);
#pragma unroll
        for (int nf = 0; nf < 4; ++nf) {
            const int rl = nf * 16 + lr;                      // W-panel row 0..63
            const int c0 = t * 8 + ((lg * 2)     ^ (rl & 7)); // phys chunk (undo swizzle)
            const int c1 = t * 8 + ((lg * 2 + 1) ^ (rl & 7));
            const f32x4 u0 = *(const f32x4*)(S + rl * 256 + c0 * 4);
            const f32x4 u1 = *(const f32x4*)(S + rl * 256 + c1 * 4);
            f16x8 h;
            h[0] = (_Float16)u0[0]; h[1] = (_Float16)u0[1];
            h[2] = (_Float16)u0[2]; h[3] = (_Float16)u0[3];
            h[4] = (_Float16)u1[0]; h[5] = (_Float16)u1[1];
            h[6] = (_Float16)u1[2]; h[7] = (_Float16)u1[3];
#pragma unroll
            for (int mf = 0; mf < 4; ++mf)
                acc[nf][mf] = __builtin_amdgcn_mfma_f32_16x16x32_f16(
                    h, xf[mf], acc[nf][mf], 0, 0, 0);
        }
    }

    // ---- epilogue: 2 passes (256 rows each) via LDS; 256B-contiguous NT stores.
    //      Raw barriers: LDS hazards are lgkm-ordered; NT stores stay in flight. ----
#pragma unroll
    for (int pass = 0; pass < 2; ++pass) {
        RAW_LDS_BARRIER();                     // pass0: K-loop reads done; pass1: prev
                                               // pass's store-side LDS reads done
        if ((w >> 2) == pass) {
            const int mloc = (w & 3) * 64;
#pragma unroll
            for (int nf = 0; nf < 4; ++nf) {
                const int gn = n0 + nf * 16 + lg * 4;
                const float4 bb = (gn < NI) ? *(const float4*)(bout + gn)
                                            : make_float4(0.f, 0.f, 0.f, 0.f);
#pragma unroll
                for (int mf = 0; mf < 4; ++mf) {
                    const int mr = mloc + mf * 16 + lr;       // 0..255
                    const int p  = (nf * 4 + lg) ^ (lr & 7);  // swizzled float4 slot
                    float4 v;
                    v.x = tanh_fast(acc[nf][mf][0] + bb.x);
                    v.y = tanh_fast(acc[nf][mf][1] + bb.y);
                    v.z = tanh_fast(acc[nf][mf][2] + bb.z);
                    v.w = tanh_fast(acc[nf][mf][3] + bb.w);
                    *(float4*)(S + mr * 64 + p * 4) = v;
                }
            }
        }
        RAW_LDS_BARRIER();                     // writers' ds_writes visible
#pragma unroll
        for (int it = 0; it < 8; ++it) {
            const int fid = it * 512 + tid;    // 0..4095
            const int row = fid >> 4;          // 0..255
            const int c   = fid & 15;          // logical float4 chunk
            const int gn  = n0 + c * 4;
            if (gn < NI) {
                const f32x4 v = *(const f32x4*)(S + row * 64 + ((c ^ (row & 7)) * 4));
                __builtin_nontemporal_store(
                    v, (f32x4*)(C + (size_t)(pass * 256 + row) * NI + gn));
            }
        }
    }
    // NT stores drain at endpgm — no trailing barrier needed.
}

extern "C" void kernel_launch(void* const* d_in, const int* in_sizes, int n_in,
                              void* d_out, int out_size, void* d_ws, size_t ws_size,
                              hipStream_t stream)
{
    const int*   idx    = (const int*)  d_in[0];
    const float* hidden = (const float*)d_in[1];   // (3,512,256)
    const float* Wih0   = (const float*)d_in[2];   // (768,100000)
    const float* WihHi  = (const float*)d_in[3];   // (2,768,256)
    const float* Whh    = (const float*)d_in[4];   // (3,768,256)
    const float* bih    = (const float*)d_in[5];   // (3,768)
    const float* bhh    = (const float*)d_in[6];   // (3,768)
    const float* Wout   = (const float*)d_in[7];   // (100000,256)
    const float* bout   = (const float*)d_in[8];   // (100000)

    float* act  = (float*)d_out;                  // (512, NI)
    float* hnew = act + (size_t)NB * NI;          // (3,512,256)
    // fp32 scratch lives in the activation region; final GEMM overwrites it.
    float* hp = act;                              // (3,512,768)
    float* xp = act + 3 * NB * H3;                // (512,768)
    // fp16 X lives in d_ws (must survive while the big GEMM writes act)
    _Float16* Xh = (_Float16*)d_ws;               // (512,256) = 256 KB

    const dim3 bs(256);
    const dim3 gs_hp(NB / 64, H3 / 64, 3);
    const dim3 gs_xp(NB / 64, H3 / 64, 1);

    // ---- all hidden-projections (depend only on input `hidden`) ----
    k_gemm_small<<<gs_hp, bs, 0, stream>>>(hidden, Whh, bhh, hp,
                                           NB, H3, NH, NB * NH, H3 * NH, H3, NB * H3);
    // ---- layer 0 (x_proj gathered inline) ----
    k_gates0<<<NB, bs, 0, stream>>>(idx, Wih0, bih, hp, hidden, hnew);
    // ---- layer 1 ----
    k_gemm_small<<<gs_xp, bs, 0, stream>>>(hnew, WihHi, bih + H3, xp,
                                           NB, H3, NH, 0, 0, 0, 0);
    k_gates<<<NB, bs, 0, stream>>>(xp, hp + NB * H3, hidden + NB * NH, hnew + NB * NH);
    // ---- layer 2 (also emits fp16 h2) ----
    k_gemm_small<<<gs_xp, bs, 0, stream>>>(hnew + NB * NH, WihHi + H3 * NH, bih + 2 * H3, xp,
                                           NB, H3, NH, 0, 0, 0, 0);
    k_gates_last<<<NB, bs, 0, stream>>>(xp, hp + 2 * NB * H3, hidden + 2 * NB * NH,
                                        hnew + 2 * NB * NH, Xh);

    // ---- output projection: 1563 n-tiles of 64, whole batch per block ----
    k_out_mfma<<<dim3((NI + 63) / 64), dim3(512), 0, stream>>>(Xh, Wout, bout, act);
}